// Round 13
// baseline (46.034 us; speedup 1.0000x reference)
//
#include <hip/hip_runtime.h>

#define NPRE 32768
#define NPOST 32768
#define RR 64
#define BATCH 512
#define KSPLIT 128
#define KCHUNK 256  // NPRE / KSPLIT

typedef float f32x4 __attribute__((ext_vector_type(4)));
typedef __bf16 bf16x8 __attribute__((ext_vector_type(8)));
typedef unsigned short u16;
typedef unsigned int u32;

static __device__ __forceinline__ float bf2f(u32 s) {
  return __builtin_bit_cast(float, s << 16);
}
// HW packed f32->bf16 (RNE): 1 VALU op for 2 elements; low16 = first arg
// (verified by k1 passing with this mapping in round 12).
static __device__ __forceinline__ u32 cvtpk(float lo, float hi) {
  u32 r;
  asm("v_cvt_pk_bf16_f32 %0, %1, %2" : "=v"(r) : "v"(lo), "v"(hi));
  return r;
}
static __device__ __forceinline__ bf16x8 pack8(f32x4 lo, f32x4 hi) {
  union { u32 w[4]; bf16x8 v; } u;
  u.w[0] = cvtpk(lo.x, lo.y);
  u.w[1] = cvtpk(lo.z, lo.w);
  u.w[2] = cvtpk(hi.x, hi.y);
  u.w[3] = cvtpk(hi.z, hi.w);
  return u.v;
}

// ---- GEMM1 (frozen from round 12): zp[kc][b][r] = S[b][kslice] @ V --------
__global__ __launch_bounds__(256, 4) void k1(const float* __restrict__ S,
                                             const float* __restrict__ V,
                                             u16* __restrict__ zp) {
  int bid = blockIdx.x;
  int eff = (bid & 7) * 128 + (bid >> 3);  // bijective XCD swizzle (1024 % 8 == 0)
  int grp = eff & 7;
  int kc = eff >> 3;                       // XCD-contiguous kc range
  int lane = threadIdx.x & 63;
  int w = threadIdx.x >> 6;
  int mt = grp * 4 + w;                    // 0..31
  int l15 = lane & 15, g = lane >> 4;
  const float* A = S + (size_t)(mt * 16 + l15) * NPRE + kc * KCHUNK + g * 8;
  const float* Vb = V + (size_t)(kc * KCHUNK + g * 8) * RR + l15;
  f32x4 acc[4] = {};
#pragma unroll 2
  for (int ks = 0; ks < KCHUNK / 32; ++ks) {
    f32x4 a0 = *reinterpret_cast<const f32x4*>(A + ks * 32);
    f32x4 a1 = *reinterpret_cast<const f32x4*>(A + ks * 32 + 4);
    bf16x8 af = pack8(a0, a1);
    const float* Vk = Vb + (size_t)ks * 32 * RR;
    bf16x8 bfr[4];
#pragma unroll
    for (int tt = 0; tt < 4; ++tt) {
      f32x4 lo, hi;
      lo.x = Vk[0 * RR + tt * 16]; lo.y = Vk[1 * RR + tt * 16];
      lo.z = Vk[2 * RR + tt * 16]; lo.w = Vk[3 * RR + tt * 16];
      hi.x = Vk[4 * RR + tt * 16]; hi.y = Vk[5 * RR + tt * 16];
      hi.z = Vk[6 * RR + tt * 16]; hi.w = Vk[7 * RR + tt * 16];
      bfr[tt] = pack8(lo, hi);
    }
    acc[0] = __builtin_amdgcn_mfma_f32_16x16x32_bf16(af, bfr[0], acc[0], 0, 0, 0);
    acc[1] = __builtin_amdgcn_mfma_f32_16x16x32_bf16(af, bfr[1], acc[1], 0, 0, 0);
    acc[2] = __builtin_amdgcn_mfma_f32_16x16x32_bf16(af, bfr[2], acc[2], 0, 0, 0);
    acc[3] = __builtin_amdgcn_mfma_f32_16x16x32_bf16(af, bfr[3], acc[3], 0, 0, 0);
  }
  u16* out = zp + ((size_t)kc * BATCH + mt * 16) * RR;
#pragma unroll
  for (int tt = 0; tt < 4; ++tt)
#pragma unroll
    for (int q = 0; q < 4; ++q)
      out[(g * 4 + q) * RR + tt * 16 + l15] = (u16)cvtpk(acc[tt][q], acc[tt][q]);
}

// ---- reduce v2: u32 pair loads, 2 outputs/thread, cvt_pk out --------------
// 64 blocks x 1024 thr (4 tg x 256 il). Wave load = 64 x 4B = 256B segments.
__global__ __launch_bounds__(1024) void k_red(const u16* __restrict__ zp,
                                              u16* __restrict__ zb) {
  __shared__ float pl[4][256], ph[4][256];
  int il = threadIdx.x & 255;
  int tg = threadIdx.x >> 8;
  int i2 = blockIdx.x * 256 + il;  // pair index, outputs {2*i2, 2*i2+1}
  const u32* p = reinterpret_cast<const u32*>(zp) +
                 (size_t)(tg * 32) * (BATCH * RR / 2) + i2;
  float sl = 0.f, sh = 0.f;
#pragma unroll
  for (int j = 0; j < 32; j += 4) {
    u32 w0 = p[(size_t)(j + 0) * (BATCH * RR / 2)];
    u32 w1 = p[(size_t)(j + 1) * (BATCH * RR / 2)];
    u32 w2 = p[(size_t)(j + 2) * (BATCH * RR / 2)];
    u32 w3 = p[(size_t)(j + 3) * (BATCH * RR / 2)];
    sl += (bf2f(w0 & 0xffffu) + bf2f(w1 & 0xffffu)) +
          (bf2f(w2 & 0xffffu) + bf2f(w3 & 0xffffu));
    sh += (bf2f(w0 >> 16) + bf2f(w1 >> 16)) + (bf2f(w2 >> 16) + bf2f(w3 >> 16));
  }
  pl[tg][il] = sl;
  ph[tg][il] = sh;
  __syncthreads();
  if (tg == 0) {
    float lo = (pl[0][il] + pl[1][il]) + (pl[2][il] + pl[3][il]);
    float hi = (ph[0][il] + ph[1][il]) + (ph[2][il] + ph[3][il]);
    reinterpret_cast<u32*>(zb)[i2] = cvtpk(lo, hi);
  }
}

// ---- GEMM2 v6: cvt_pk staging + zb preload --------------------------------
// 512 blocks x 512 thr. Changes vs v5-fallback: (1) staging uses HW cvt_pk
// (~4x fewer VALU ops before the barrier); (2) all 8 zb fragments preloaded
// before staging so the compute loop has zero global loads.
__global__ __launch_bounds__(512, 4) void k2(const u16* __restrict__ zv,
                                             const float* __restrict__ U,
                                             float* __restrict__ y) {
  __shared__ u16 Ub[512 * 64];  // 64 KB, byte = (row*128+col*2)^((row&7)<<4)
  int bid = blockIdx.x;
  int eff = (bid & 7) * 64 + (bid >> 3);  // bijective (512 % 8 == 0)
  int nt = eff >> 3;                      // 8 consecutive n-tiles per XCD
  int bg = eff & 7;
  int n0 = nt * 512;
  int t = threadIdx.x;
  int lane = t & 63;
  int w = t >> 6;
  int l15 = lane & 15, g = lane >> 4;
  char* Uc = reinterpret_cast<char*>(Ub);

  // preload all zb fragments (L2-hot, independent of LDS staging)
  bf16x8 za[4], zc[4];
#pragma unroll
  for (int it = 0; it < 4; ++it) {
    const u16* A = zv + (size_t)(bg * 64 + it * 16 + l15) * RR + g * 8;
    za[it] = *reinterpret_cast<const bf16x8*>(A);
    zc[it] = *reinterpret_cast<const bf16x8*>(A + 32);
  }

  // stage U slice -> LDS bf16 via cvt_pk: 32768 floats = 16 x 512thr x 4
#pragma unroll
  for (int i = 0; i < 16; ++i) {
    int f = i * 2048 + t * 4;
    int row = f >> 6;
    int colb = (f & 63) * 2;
    f32x4 u = *reinterpret_cast<const f32x4*>(U + (size_t)n0 * RR + f);
    uint2 pk;
    pk.x = cvtpk(u.x, u.y);
    pk.y = cvtpk(u.z, u.w);
    *reinterpret_cast<uint2*>(Uc + ((row * 128 + colb) ^ ((row & 7) << 4))) = pk;
  }
  __syncthreads();

#pragma unroll
  for (int it = 0; it < 4; ++it) {
    int b0 = bg * 64 + it * 16;
    f32x4 acc[4] = {};
#pragma unroll
    for (int j = 0; j < 4; ++j) {
      int tau = w + 8 * j;
      int row = tau * 16 + l15;
      int base = row * 128;
      int swz = (row & 7) << 4;
      bf16x8 uA = *reinterpret_cast<const bf16x8*>(Uc + ((base + g * 16) ^ swz));
      bf16x8 uB = *reinterpret_cast<const bf16x8*>(Uc + ((base + 64 + g * 16) ^ swz));
      acc[j] = __builtin_amdgcn_mfma_f32_16x16x32_bf16(uA, za[it], acc[j], 0, 0, 0);
      acc[j] = __builtin_amdgcn_mfma_f32_16x16x32_bf16(uB, zc[it], acc[j], 0, 0, 0);
    }
    float* yb = y + (size_t)(b0 + l15) * NPOST + n0;
#pragma unroll
    for (int j = 0; j < 4; ++j) {
      int tau = w + 8 * j;
      *reinterpret_cast<f32x4*>(yb + tau * 16 + g * 4) = acc[j];
    }
  }
}

extern "C" void kernel_launch(void* const* d_in, const int* in_sizes, int n_in,
                              void* d_out, int out_size, void* d_ws, size_t ws_size,
                              hipStream_t stream) {
  const float* spikes = (const float*)d_in[0];
  const float* U = (const float*)d_in[1];
  const float* V = (const float*)d_in[2];
  // d_in[3..5]: CSR mask — dead in the reference, unused.
  float* y = (float*)d_out;
  char* ws = (char*)d_ws;
  u16* zp = (u16*)ws;                    // 8 MiB  [KSPLIT][BATCH][RR] bf16
  u16* zb = (u16*)(ws + (8u << 20));     // 64 KiB [BATCH][RR] bf16

  k1<<<1024, 256, 0, stream>>>(spikes, V, zp);
  k_red<<<64, 1024, 0, stream>>>(zp, zb);
  k2<<<512, 512, 0, stream>>>(zb, U, y);
}